// Round 11
// baseline (365.046 us; speedup 1.0000x reference)
//
#include <hip/hip_runtime.h>
#include <hip/hip_fp16.h>

// ============================================================================
// INSTRUMENTATION ROUND: layer16 and partb run their bodies TWICE (identical
// output bytes; asm memory clobber defeats cross-rep CSE). This doubles their
// dispatch durations above the harness fill floor (~44 us) so the rocprof
// top-5 finally shows their counters. total' - 241.8 = 3*L + partb closes the
// budget. Numerics identical (reps write identical bytes; partb rep-1 rebuild
// only permutes within-(row,srcbucket) ELL order = fp32 rounding noise, same
// class of nondeterminism the pipeline already has).
// ============================================================================

typedef __attribute__((ext_vector_type(8))) _Float16 half8;
typedef __attribute__((ext_vector_type(4))) float f32x4;
typedef unsigned int u32;
typedef unsigned short u16;
typedef unsigned long long u64;

#define ELL_PAD 64
#define BKT 64
#define BKT_SH 6
#define EPB 1024
#define NAMAX 640
#define RUNCAP 1536

// ---------- K1: zero deg_out + phantom pad rows of xh + pack W ----------

__global__ __launch_bounds__(256) void initpack(int* __restrict__ deg_out,
                                                u32* __restrict__ xz0,
                                                u32* __restrict__ xz1,
                                                const float* __restrict__ Ws,
                                                _Float16* __restrict__ Whi,
                                                _Float16* __restrict__ Wlo,
                                                int N, int padU32, int zb, int packTotal) {
  int b = blockIdx.x;
  if (b < zb) {
    int i = b * 256 + threadIdx.x;
    if (i < N) deg_out[i] = 0;
    if (b == 0) {
      for (int j = threadIdx.x; j < padU32; j += 256) { xz0[j] = 0; xz1[j] = 0; }
    }
    return;
  }
  int i = (b - zb) * 256 + threadIdx.x;
  if (i < packTotal) {
    int lane  = i & 63;
    int kstep = (i >> 6) & 3;
    int ntile = (i >> 8) & 7;
    int layer = i >> 11;
    int nn = ntile * 16 + (lane & 15);
    int k0 = kstep * 32 + (lane >> 4) * 8;
    const float* W = Ws + (size_t)layer * 128 * 128;
    size_t base = (size_t)i * 8;
    for (int j = 0; j < 8; j++) {
      float v = W[(k0 + j) * 128 + nn];
      _Float16 hi = (_Float16)v;
      Whi[base + j] = hi;
      Wlo[base + j] = (_Float16)(v - (float)hi);   // exact residual
    }
  }
}

// ---------- K2a: block-local counting sort of edges into dst-buckets ----------
// (single-shot: deg_out atomics are not idempotent; parta time is inferred as
//  total - init - partb - 3L - gaps)

__global__ __launch_bounds__(512) void parta(const int* __restrict__ esrc,
                                             const int* __restrict__ edst,
                                             int* __restrict__ deg_out,
                                             u32* __restrict__ part,
                                             u32* __restrict__ runTab,
                                             int E, int NB) {
  __shared__ u32 hist[1024];
  __shared__ u32 stage[EPB];
  __shared__ u32 scanA[512];
  int a = blockIdx.x;
  int e0 = a * EPB;
  int e1 = min(E, e0 + EPB);
  int len = e1 - e0;
  int tid = threadIdx.x;
  for (int j = tid; j <= NB; j += 512) hist[j] = 0;
  __syncthreads();
  for (int i = e0 + tid; i < e1; i += 512) {
    int s = esrc[i];
    int d = edst[i];
    atomicAdd(&deg_out[s], 1);
    atomicAdd(&hist[d >> BKT_SH], 1u);
  }
  __syncthreads();
  int i0 = 2 * tid, i1 = 2 * tid + 1;
  u32 c0 = (i0 < NB) ? hist[i0] : 0;
  u32 c1 = (i1 < NB) ? hist[i1] : 0;
  u32 s2 = c0 + c1;
  scanA[tid] = s2;
  __syncthreads();
  for (int off = 1; off < 512; off <<= 1) {
    u32 t2 = scanA[tid] + ((tid >= off) ? scanA[tid - off] : 0);
    __syncthreads();
    scanA[tid] = t2;
    __syncthreads();
  }
  u32 base = scanA[tid] - s2;
  u32* rt = runTab + (size_t)a * (NB + 1);
  if (i0 < NB) { rt[i0] = base;      hist[i0] = base; }
  if (i1 < NB) { rt[i1] = base + c0; hist[i1] = base + c0; }
  if (tid == 0) rt[NB] = (u32)len;
  __syncthreads();
  for (int i = e0 + tid; i < e1; i += 512) {
    int s = esrc[i];
    int d = edst[i];
    u32 p = atomicAdd(&hist[d >> BKT_SH], 1u);
    stage[p] = (u32)s | ((u32)(d & (BKT - 1)) << 16);
  }
  __syncthreads();
  u32* op = part + (size_t)a * EPB;
  for (int j = tid; j < len; j += 512) op[j] = stage[j];
}

// ---------- K2b: per-bucket ELL build + fused xscale — SELF-DOUBLED ----------

__global__ __launch_bounds__(512) void partb(const u32* __restrict__ part,
                                             const u32* __restrict__ runTab,
                                             const float* __restrict__ x,
                                             const int* __restrict__ deg_out,
                                             int* __restrict__ deg_in,
                                             u16* __restrict__ ell,
                                             __half2* __restrict__ xh,
                                             int N, int NA, int NB) {
  __shared__ u16 slice[BKT * ELL_PAD];
  __shared__ u32 cnt2[BKT * 17];
  __shared__ u32 roff[NAMAX + 1];
  __shared__ u32 rbase[NAMAX];
  __shared__ u16 runid[RUNCAP];
  __shared__ u32 pstage[RUNCAP];
  __shared__ u32 scanB[512];
  int b = blockIdx.x;
  int base = b * BKT;
  int hi = min(BKT, N - base);
  if (hi <= 0) return;
  int tid = threadIdx.x;

  for (int rep = 0; rep < 2; rep++) {        // INSTRUMENTATION x2
  u32 nv = ((u32)N << 16) | (u32)N;
  u32* s32 = (u32*)slice;
  for (int j = tid; j < BKT * (ELL_PAD / 2); j += 512) s32[j] = nv;
  for (int j = tid; j < BKT * 17; j += 512) cnt2[j] = 0;
  int a0 = 2 * tid, a1 = 2 * tid + 1;
  u32 l0 = 0, l1 = 0;
  if (a0 < NA) {
    u32 s = runTab[(size_t)a0 * (NB + 1) + b];
    u32 e = runTab[(size_t)a0 * (NB + 1) + b + 1];
    l0 = e - s;
    rbase[a0] = (u32)a0 * EPB + s;
  }
  if (a1 < NA) {
    u32 s = runTab[(size_t)a1 * (NB + 1) + b];
    u32 e = runTab[(size_t)a1 * (NB + 1) + b + 1];
    l1 = e - s;
    rbase[a1] = (u32)a1 * EPB + s;
  }
  u32 s2 = l0 + l1;
  scanB[tid] = s2;
  __syncthreads();
  for (int off = 1; off < 512; off <<= 1) {
    u32 t2 = scanB[tid] + ((tid >= off) ? scanB[tid - off] : 0);
    __syncthreads();
    scanB[tid] = t2;
    __syncthreads();
  }
  u32 pbase = scanB[tid] - s2;
  if (a0 < NA) roff[a0] = pbase;
  if (a1 < NA) roff[a1] = pbase + l0;
  if (tid == 511) roff[NA] = scanB[511];
  __syncthreads();
  int T = (int)roff[NA];
  for (int a = tid; a < NA; a += 512) {
    u32 s0 = roff[a];
    u32 l = roff[a + 1] - s0;
    for (u32 k = 0; k < l; k++)
      if (s0 + k < RUNCAP) runid[s0 + k] = (u16)a;
  }
  __syncthreads();
  for (int i = tid; i < T; i += 512) {
    int a;
    if (i < RUNCAP) a = runid[i];
    else {
      int lo = 0, hh = NA;
      while (hh - lo > 1) { int mid = (lo + hh) >> 1; if (roff[mid] <= (u32)i) lo = mid; else hh = mid; }
      a = lo;
    }
    u32 pair = part[(size_t)rbase[a] + ((u32)i - roff[a])];
    if (i < RUNCAP) pstage[i] = pair;
    u32 dl = pair >> 16;
    u32 src = pair & 0xFFFFu;
    atomicAdd(&cnt2[dl * 17 + (src >> 12)], 1u);
  }
  __syncthreads();
  if (tid < BKT) {
    u32 run = 0;
    for (int bk = 0; bk < 16; bk++) {
      u32 t2 = cnt2[tid * 17 + bk];
      cnt2[tid * 17 + bk] = run;
      run += t2;
    }
    if (tid < hi) deg_in[base + tid] = (int)run;
  }
  __syncthreads();
  for (int i = tid; i < T; i += 512) {
    u32 pair;
    if (i < RUNCAP) pair = pstage[i];
    else {
      int lo = 0, hh = NA;
      while (hh - lo > 1) { int mid = (lo + hh) >> 1; if (roff[mid] <= (u32)i) lo = mid; else hh = mid; }
      pair = part[(size_t)rbase[lo] + ((u32)i - roff[lo])];
    }
    u32 dl = pair >> 16;
    u32 src = pair & 0xFFFFu;
    u32 p = atomicAdd(&cnt2[dl * 17 + (src >> 12)], 1u);
    if (p < ELL_PAD) slice[dl * ELL_PAD + p] = (u16)src;
  }
  __syncthreads();
  u32* eg = (u32*)(ell + (size_t)base * ELL_PAD);
  for (int j = tid; j < hi * (ELL_PAD / 2); j += 512) eg[j] = s32[j];
  float* sc = (float*)scanB;
  if (tid < hi) {
    int d = deg_out[base + tid]; if (d < 1) d = 1;
    sc[tid] = rsqrtf((float)d);
  }
  __syncthreads();
  for (int j = tid; j < hi * 64; j += 512) {
    int r = j >> 6, c = j & 63;
    float s = sc[r];
    float2 v = ((const float2*)x)[(size_t)(base + r) * 64 + c];
    xh[(size_t)(base + r) * 64 + c] = __floats2half2_rn(v.x * s, v.y * s);
  }
  __syncthreads();                            // rep isolation
  asm volatile("" ::: "memory");              // defeat cross-rep CSE/DCE
  }  // rep
}

// ---------- K4: fused layer — 16-row tile, 8 waves — SELF-DOUBLED ----------

__global__ __launch_bounds__(512) void layer16(const _Float16* __restrict__ xh,
                                               const int* __restrict__ deg_in,
                                               const u16* __restrict__ ell,
                                               const _Float16* __restrict__ Whi,
                                               const _Float16* __restrict__ Wlo,
                                               const float* __restrict__ bias,
                                               const int* __restrict__ deg_out,
                                               __half* __restrict__ out16,
                                               float* __restrict__ out32, int n) {
  __shared__ _Float16 As[16 * 136];
  const int wave = threadIdx.x >> 6;
  const int lane = threadIdx.x & 63;
  const int sub  = lane & 15;
  const int grp  = lane >> 4;
  const int sh   = grp << 4;
  const u32 sub16 = (u32)sub * 16u;
  const int rowBase = blockIdx.x * 16;
  const char* __restrict__ xb = (const char*)xh;

  for (int rep = 0; rep < 2; rep++) {        // INSTRUMENTATION x2
  // ---- gather phase: 2 rows per wave
  {
    int r0 = rowBase + wave * 2, r1 = r0 + 1;
    int d0 = (r0 < n) ? deg_in[r0] : 0;
    int d1 = (r1 < n) ? deg_in[r1] : 0;
    int l0 = d0 > ELL_PAD ? ELL_PAD : d0;
    int l1 = d1 > ELL_PAD ? ELL_PAD : d1;
    int t0 = (l0 + 3) & ~3;
    int t1 = (l1 + 3) & ~3;
    const u16* ep0 = ell + (u32)(r0 < n ? r0 : 0) * ELL_PAD;
    const u16* ep1 = ell + (u32)(r1 < n ? r1 : 0) * ELL_PAD;

    float a0[8] = {0.f, 0.f, 0.f, 0.f, 0.f, 0.f, 0.f, 0.f};
    float a1[8] = {0.f, 0.f, 0.f, 0.f, 0.f, 0.f, 0.f, 0.f};

    int m = t0 < t1 ? t0 : t1;
    int e = 0;
    for (; e + 8 <= m; e += 8) {
      u64 wa0 = *(const u64*)&ep0[e];
      u64 wa1 = *(const u64*)&ep0[e + 4];
      u64 wb0 = *(const u64*)&ep1[e];
      u64 wb1 = *(const u64*)&ep1[e + 4];
      u32 ia0 = ((u32)(wa0 >> sh) & 0xFFFFu) * 256u + sub16;
      u32 ia1 = ((u32)(wa1 >> sh) & 0xFFFFu) * 256u + sub16;
      u32 ib0 = ((u32)(wb0 >> sh) & 0xFFFFu) * 256u + sub16;
      u32 ib1 = ((u32)(wb1 >> sh) & 0xFFFFu) * 256u + sub16;
      half8 va0 = *(const half8*)(xb + ia0);
      half8 va1 = *(const half8*)(xb + ia1);
      half8 vb0 = *(const half8*)(xb + ib0);
      half8 vb1 = *(const half8*)(xb + ib1);
#pragma unroll
      for (int j = 0; j < 8; j++) {
        a0[j] += (float)va0[j] + (float)va1[j];
        a1[j] += (float)vb0[j] + (float)vb1[j];
      }
    }
    for (; e < m; e += 4) {
      u64 wa = *(const u64*)&ep0[e];
      u64 wb = *(const u64*)&ep1[e];
      u32 ia = ((u32)(wa >> sh) & 0xFFFFu) * 256u + sub16;
      u32 ib = ((u32)(wb >> sh) & 0xFFFFu) * 256u + sub16;
      half8 va = *(const half8*)(xb + ia);
      half8 vb = *(const half8*)(xb + ib);
#pragma unroll
      for (int j = 0; j < 8; j++) { a0[j] += (float)va[j]; a1[j] += (float)vb[j]; }
    }
    for (int ea = m; ea < t0; ea += 4) {
      u64 wa = *(const u64*)&ep0[ea];
      u32 ia = ((u32)(wa >> sh) & 0xFFFFu) * 256u + sub16;
      half8 va = *(const half8*)(xb + ia);
#pragma unroll
      for (int j = 0; j < 8; j++) a0[j] += (float)va[j];
    }
    for (int eb = m; eb < t1; eb += 4) {
      u64 wb = *(const u64*)&ep1[eb];
      u32 ib = ((u32)(wb >> sh) & 0xFFFFu) * 256u + sub16;
      half8 vb = *(const half8*)(xb + ib);
#pragma unroll
      for (int j = 0; j < 8; j++) a1[j] += (float)vb[j];
    }

#pragma unroll
    for (int j = 0; j < 8; j++) {
      a0[j] += __shfl_xor(a0[j], 16, 64);
      a0[j] += __shfl_xor(a0[j], 32, 64);
      a1[j] += __shfl_xor(a1[j], 16, 64);
      a1[j] += __shfl_xor(a1[j], 32, 64);
    }

    float si0 = rsqrtf((float)(d0 < 1 ? 1 : d0));
    float si1 = rsqrtf((float)(d1 < 1 ? 1 : d1));
    if (grp == 0) {
      half8 h0, h1;
#pragma unroll
      for (int j = 0; j < 8; j++) {
        h0[j] = (_Float16)(a0[j] * si0);
        h1[j] = (_Float16)(a1[j] * si1);
      }
      *(half8*)&As[(wave * 2 + 0) * 136 + sub * 8] = h0;
      *(half8*)&As[(wave * 2 + 1) * 136 + sub * 8] = h1;
    }
  }
  __syncthreads();

  // ---- GEMM phase
  f32x4 acc = (f32x4){0.f, 0.f, 0.f, 0.f};
#pragma unroll
  for (int ks = 0; ks < 4; ks++) {
    half8 a  = *(const half8*)&As[(size_t)sub * 136 + ks * 32 + grp * 8];
    half8 bh = *(const half8*)&Whi[((wave * 4 + ks) * 64 + lane) * 8];
    half8 bl = *(const half8*)&Wlo[((wave * 4 + ks) * 64 + lane) * 8];
    acc = __builtin_amdgcn_mfma_f32_16x16x32_f16(a, bh, acc, 0, 0, 0);
    acc = __builtin_amdgcn_mfma_f32_16x16x32_f16(a, bl, acc, 0, 0, 0);
  }

  const int r0c = rowBase + grp * 4;
  const int col = wave * 16 + sub;
  const float bv = bias[col];
#pragma unroll
  for (int r = 0; r < 4; r++) {
    int row = r0c + r;
    if (row < n) {
      float v = fmaxf(acc[r] + bv, 0.f);
      if (out16) {
        int d = deg_out[row]; if (d < 1) d = 1;
        out16[(size_t)row * 128 + col] = __float2half(v * rsqrtf((float)d));
      } else {
        out32[(size_t)row * 128 + col] = v;
      }
    }
  }
  __syncthreads();                            // rep isolation (As reuse)
  asm volatile("" ::: "memory");              // defeat cross-rep CSE/DCE
  }  // rep
}

// ---------- launch ----------

extern "C" void kernel_launch(void* const* d_in, const int* in_sizes, int n_in,
                              void* d_out, int out_size, void* d_ws, size_t ws_size,
                              hipStream_t stream) {
  const float* x   = (const float*)d_in[0];
  const float* Ws  = (const float*)d_in[1];
  const float* bs  = (const float*)d_in[2];
  const int* esrc  = (const int*)d_in[3];
  const int* edst  = (const int*)d_in[4];

  const int D = 128;
  const int N = in_sizes[0] / D;
  const int E = in_sizes[3];
  const int L = in_sizes[1] / (D * D);
  const int Npad = ((N + 15) / 16) * 16;
  const int NA = (E + EPB - 1) / EPB;
  const int NB = (N + BKT - 1) / BKT;

  char* base = (char*)d_ws;
  size_t off = 0;
  auto alloc = [&](size_t bytes) {
    char* p = base + off;
    off = (off + bytes + 255) & ~(size_t)255;
    return p;
  };
  int*      deg_out = (int*)alloc((size_t)N * 4);
  int*      deg_in  = (int*)alloc((size_t)N * 4);
  u16*      ell     = (u16*)alloc((size_t)N * ELL_PAD * 2);
  _Float16* Whi     = (_Float16*)alloc((size_t)L * 16384 * 2);
  _Float16* Wlo     = (_Float16*)alloc((size_t)L * 16384 * 2);
  _Float16* xh0     = (_Float16*)alloc((size_t)(Npad + 16) * 128 * 2);
  _Float16* xh1     = (_Float16*)alloc((size_t)(Npad + 16) * 128 * 2);
  u32*      part    = (u32*)alloc((size_t)NA * EPB * 4);
  u32*      runTab  = (u32*)alloc((size_t)NA * (NB + 1) * 4);

  const int zb = (N + 255) / 256;
  const int packTotal = L * 2048;
  const int packB = (packTotal + 255) / 256;
  const int padU32 = 16 * 64;

  initpack<<<dim3(zb + packB), dim3(256), 0, stream>>>(
      deg_out,
      (u32*)(xh0 + (size_t)N * 128), (u32*)(xh1 + (size_t)N * 128),
      Ws, Whi, Wlo, N, padU32, zb, packTotal);
  parta<<<dim3(NA), dim3(512), 0, stream>>>(
      esrc, edst, deg_out, part, runTab, E, NB);
  partb<<<dim3(NB), dim3(512), 0, stream>>>(
      part, runTab, x, deg_out, deg_in, ell, (__half2*)xh0, N, NA, NB);

  float* outf = (float*)d_out;
  _Float16* ping[2] = {xh0, xh1};
  const dim3 lgrid(Npad / 16), lblk(512);

  for (int l = 0; l < L; l++) {
    bool last = (l == L - 1);
    layer16<<<lgrid, lblk, 0, stream>>>(
        (const _Float16*)ping[l & 1], deg_in, ell,
        Whi + (size_t)l * 16384, Wlo + (size_t)l * 16384,
        bs + (size_t)l * D, deg_out,
        last ? nullptr : (__half*)ping[(l + 1) & 1],
        last ? outf : nullptr, N);
  }
}

// Round 12
// 222.496 us; speedup vs baseline: 1.6407x; 1.6407x over previous
//
#include <hip/hip_runtime.h>
#include <hip/hip_fp16.h>

typedef __attribute__((ext_vector_type(8))) _Float16 half8;
typedef __attribute__((ext_vector_type(4))) float f32x4;
typedef unsigned int u32;
typedef unsigned short u16;
typedef unsigned long long u64;

#define ELL_PAD 64
#define BKT 64           // nodes per bucket (both src and dst sides)
#define BKT_SH 6
#define EPB 1024         // edges per parta block (625 blocks for E=640K)
#define NAMAX 640
#define RUNCAP 1536      // staged-pairs capacity (dst bucket load ~819 +- 29)

// ---------- K1: phantom pad rows of xh + pack W (deg_out zeroing GONE — it is
// now densely written by partb's src-side count) ----------
// Pack layout (B-fragment order for mfma_f32_16x16x32_f16):
// elem j of (layer,ntile,kstep,lane) = W[k=kstep*32+(lane>>4)*8+j][n=ntile*16+(lane&15)]

__global__ __launch_bounds__(256) void initpack(u32* __restrict__ xz0,
                                                u32* __restrict__ xz1,
                                                const float* __restrict__ Ws,
                                                _Float16* __restrict__ Whi,
                                                _Float16* __restrict__ Wlo,
                                                int padU32, int packTotal) {
  int b = blockIdx.x;
  if (b == 0) {
    for (int j = threadIdx.x; j < padU32; j += 256) { xz0[j] = 0; xz1[j] = 0; }
    return;
  }
  int i = (b - 1) * 256 + threadIdx.x;
  if (i < packTotal) {
    int lane  = i & 63;
    int kstep = (i >> 6) & 3;
    int ntile = (i >> 8) & 7;
    int layer = i >> 11;
    int nn = ntile * 16 + (lane & 15);
    int k0 = kstep * 32 + (lane >> 4) * 8;
    const float* W = Ws + (size_t)layer * 128 * 128;
    size_t base = (size_t)i * 8;
    for (int j = 0; j < 8; j++) {
      float v = W[(k0 + j) * 128 + nn];
      _Float16 hi = (_Float16)v;
      Whi[base + j] = hi;
      Wlo[base + j] = (_Float16)(v - (float)hi);   // exact residual
    }
  }
}

// ---------- K2a: DUAL counting sort (dst-keyed pairs + src-keyed locals) ----------
// ZERO global atomics. Dst side: {src,dstLocal} pairs ordered by dst bucket
// (feeds ELL build). Src side: src&63 ordered by src bucket (feeds deg_out
// count). All histogramming/scanning in LDS; all global writes dense.

__global__ __launch_bounds__(512) void parta(const int* __restrict__ esrc,
                                             const int* __restrict__ edst,
                                             u32* __restrict__ part,
                                             u32* __restrict__ runTab,
                                             u16* __restrict__ partS,
                                             u32* __restrict__ runTabS,
                                             int E, int NB) {
  __shared__ u32 histD[1024];     // NB+1 <= 1024
  __shared__ u32 histS[1024];
  __shared__ u32 stageD[EPB];     // 4 KB
  __shared__ u16 stageS[EPB];     // 2 KB
  __shared__ u32 scanA[512];
  int a = blockIdx.x;
  int e0 = a * EPB;
  int e1 = min(E, e0 + EPB);
  int len = e1 - e0;
  int tid = threadIdx.x;
  for (int j = tid; j <= NB; j += 512) { histD[j] = 0; histS[j] = 0; }
  __syncthreads();
  // pass 1: dual histogram (LDS only)
  for (int i = e0 + tid; i < e1; i += 512) {
    int s = esrc[i];
    int d = edst[i];
    atomicAdd(&histD[d >> BKT_SH], 1u);
    atomicAdd(&histS[s >> BKT_SH], 1u);
  }
  __syncthreads();
  // scan D (2-elem/thread Hillis-Steele)
  {
    int i0 = 2 * tid, i1 = 2 * tid + 1;
    u32 c0 = (i0 < NB) ? histD[i0] : 0;
    u32 c1 = (i1 < NB) ? histD[i1] : 0;
    u32 s2 = c0 + c1;
    scanA[tid] = s2;
    __syncthreads();
    for (int off = 1; off < 512; off <<= 1) {
      u32 t2 = scanA[tid] + ((tid >= off) ? scanA[tid - off] : 0);
      __syncthreads();
      scanA[tid] = t2;
      __syncthreads();
    }
    u32 base = scanA[tid] - s2;
    u32* rt = runTab + (size_t)a * (NB + 1);
    if (i0 < NB) { rt[i0] = base;      histD[i0] = base; }
    if (i1 < NB) { rt[i1] = base + c0; histD[i1] = base + c0; }
    if (tid == 0) rt[NB] = (u32)len;
  }
  __syncthreads();
  // scan S
  {
    int i0 = 2 * tid, i1 = 2 * tid + 1;
    u32 c0 = (i0 < NB) ? histS[i0] : 0;
    u32 c1 = (i1 < NB) ? histS[i1] : 0;
    u32 s2 = c0 + c1;
    scanA[tid] = s2;
    __syncthreads();
    for (int off = 1; off < 512; off <<= 1) {
      u32 t2 = scanA[tid] + ((tid >= off) ? scanA[tid - off] : 0);
      __syncthreads();
      scanA[tid] = t2;
      __syncthreads();
    }
    u32 base = scanA[tid] - s2;
    u32* rt = runTabS + (size_t)a * (NB + 1);
    if (i0 < NB) { rt[i0] = base;      histS[i0] = base; }
    if (i1 < NB) { rt[i1] = base + c0; histS[i1] = base + c0; }
    if (tid == 0) rt[NB] = (u32)len;
  }
  __syncthreads();
  // pass 2: place into both stagings (edges L2-hot re-read)
  for (int i = e0 + tid; i < e1; i += 512) {
    int s = esrc[i];
    int d = edst[i];
    u32 pD = atomicAdd(&histD[d >> BKT_SH], 1u);
    stageD[pD] = (u32)s | ((u32)(d & (BKT - 1)) << 16);
    u32 pS = atomicAdd(&histS[s >> BKT_SH], 1u);
    stageS[pS] = (u16)(s & (BKT - 1));
  }
  __syncthreads();
  // pass 3: dense coalesced writes
  u32* opD = part + (size_t)a * EPB;
  for (int j = tid; j < len; j += 512) opD[j] = stageD[j];
  u16* opS = partS + (size_t)a * EPB;
  for (int j = tid; j < len; j += 512) opS[j] = stageS[j];
}

// ---------- K2b: per-bucket ELL build + src-count deg_out + fused xscale ----------
// Dst side: ELL slice (src-bucket-sorted rows) + deg_in, as proven. Src side:
// count partS items into 64 LDS counters -> dense deg_out write -> xscale of
// this bucket's 64 rows. Self-contained per bucket; no cross-kernel deg_out
// dependency and zero global atomics anywhere.

__global__ __launch_bounds__(512) void partb(const u32* __restrict__ part,
                                             const u32* __restrict__ runTab,
                                             const u16* __restrict__ partS,
                                             const u32* __restrict__ runTabS,
                                             const float* __restrict__ x,
                                             int* __restrict__ deg_out,
                                             int* __restrict__ deg_in,
                                             u16* __restrict__ ell,
                                             __half2* __restrict__ xh,
                                             int N, int NA, int NB) {
  __shared__ u16 slice[BKT * ELL_PAD];   // 8 KB
  __shared__ u32 cnt2[BKT * 17];         // 4.3 KB
  __shared__ u32 roff[NAMAX + 1];
  __shared__ u32 rbase[NAMAX];
  __shared__ u16 runid[RUNCAP];          // 3 KB
  __shared__ u32 pstage[RUNCAP];         // 6 KB
  __shared__ u32 scanB[512];
  __shared__ u32 cntS[BKT];
  int b = blockIdx.x;
  int base = b * BKT;
  int hi = min(BKT, N - base);
  if (hi <= 0) return;
  int tid = threadIdx.x;

  u32 nv = ((u32)N << 16) | (u32)N;      // two phantom entries
  u32* s32 = (u32*)slice;
  for (int j = tid; j < BKT * (ELL_PAD / 2); j += 512) s32[j] = nv;
  for (int j = tid; j < BKT * 17; j += 512) cnt2[j] = 0;
  if (tid < BKT) cntS[tid] = 0;
  // dst-side: run lengths + scan (2-elem/thread)
  int a0 = 2 * tid, a1 = 2 * tid + 1;
  u32 l0 = 0, l1 = 0;
  if (a0 < NA) {
    u32 s = runTab[(size_t)a0 * (NB + 1) + b];
    u32 e = runTab[(size_t)a0 * (NB + 1) + b + 1];
    l0 = e - s;
    rbase[a0] = (u32)a0 * EPB + s;
  }
  if (a1 < NA) {
    u32 s = runTab[(size_t)a1 * (NB + 1) + b];
    u32 e = runTab[(size_t)a1 * (NB + 1) + b + 1];
    l1 = e - s;
    rbase[a1] = (u32)a1 * EPB + s;
  }
  u32 s2 = l0 + l1;
  scanB[tid] = s2;
  __syncthreads();
  for (int off = 1; off < 512; off <<= 1) {
    u32 t2 = scanB[tid] + ((tid >= off) ? scanB[tid - off] : 0);
    __syncthreads();
    scanB[tid] = t2;
    __syncthreads();
  }
  u32 pbase = scanB[tid] - s2;
  if (a0 < NA) roff[a0] = pbase;
  if (a1 < NA) roff[a1] = pbase + l0;
  if (tid == 511) roff[NA] = scanB[511];
  __syncthreads();
  int T = (int)roff[NA];
  for (int a = tid; a < NA; a += 512) {
    u32 s0 = roff[a];
    u32 l = roff[a + 1] - s0;
    for (u32 k = 0; k < l; k++)
      if (s0 + k < RUNCAP) runid[s0 + k] = (u16)a;
  }
  __syncthreads();
  // src-side count (cheap: ~1.3 items/run avg) — overlaps dst-side latency
  for (int a = tid; a < NA; a += 512) {
    u32 s = runTabS[(size_t)a * (NB + 1) + b];
    u32 e = runTabS[(size_t)a * (NB + 1) + b + 1];
    const u16* ps = partS + (size_t)a * EPB;
    for (u32 k = s; k < e; k++) atomicAdd(&cntS[ps[k]], 1u);
  }
  // dst pass A: read part once, stage pair, count (row, srcbucket)
  for (int i = tid; i < T; i += 512) {
    int a;
    if (i < RUNCAP) a = runid[i];
    else {
      int lo = 0, hh = NA;
      while (hh - lo > 1) { int mid = (lo + hh) >> 1; if (roff[mid] <= (u32)i) lo = mid; else hh = mid; }
      a = lo;
    }
    u32 pair = part[(size_t)rbase[a] + ((u32)i - roff[a])];
    if (i < RUNCAP) pstage[i] = pair;
    u32 dl = pair >> 16;
    u32 src = pair & 0xFFFFu;
    atomicAdd(&cnt2[dl * 17 + (src >> 12)], 1u);
  }
  __syncthreads();
  // per-row exclusive prefix over 16 src-buckets; emit deg_in + deg_out
  if (tid < BKT) {
    u32 run = 0;
    for (int bk = 0; bk < 16; bk++) {
      u32 t2 = cnt2[tid * 17 + bk];
      cnt2[tid * 17 + bk] = run;
      run += t2;
    }
    if (tid < hi) {
      deg_in[base + tid] = (int)run;
      deg_out[base + tid] = (int)cntS[tid];
    }
  }
  __syncthreads();
  // dst pass B: place at bucket cursors -> row sorted by src bucket
  for (int i = tid; i < T; i += 512) {
    u32 pair;
    if (i < RUNCAP) pair = pstage[i];
    else {
      int lo = 0, hh = NA;
      while (hh - lo > 1) { int mid = (lo + hh) >> 1; if (roff[mid] <= (u32)i) lo = mid; else hh = mid; }
      pair = part[(size_t)rbase[lo] + ((u32)i - roff[lo])];
    }
    u32 dl = pair >> 16;
    u32 src = pair & 0xFFFFu;
    u32 p = atomicAdd(&cnt2[dl * 17 + (src >> 12)], 1u);
    if (p < ELL_PAD) slice[dl * ELL_PAD + p] = (u16)src;
  }
  __syncthreads();
  u32* eg = (u32*)(ell + (size_t)base * ELL_PAD);
  for (int j = tid; j < hi * (ELL_PAD / 2); j += 512) eg[j] = s32[j];
  // ---- fused xscale for rows [base, base+hi) using this bucket's cntS
  float* sc = (float*)scanB;
  if (tid < hi) {
    u32 d = cntS[tid]; if (d < 1) d = 1;
    sc[tid] = rsqrtf((float)d);
  }
  __syncthreads();
  for (int j = tid; j < hi * 64; j += 512) {
    int r = j >> 6, c = j & 63;
    float s = sc[r];
    float2 v = ((const float2*)x)[(size_t)(base + r) * 64 + c];
    xh[(size_t)(base + r) * 64 + c] = __floats2half2_rn(v.x * s, v.y * s);
  }
}

// ---------- K4: fused layer — 16-row tile, 8 waves (proven r4 body, measured
// at its random-gather roofline ~4.5 TB/s — unchanged) ----------

__global__ __launch_bounds__(512) void layer16(const _Float16* __restrict__ xh,
                                               const int* __restrict__ deg_in,
                                               const u16* __restrict__ ell,
                                               const _Float16* __restrict__ Whi,
                                               const _Float16* __restrict__ Wlo,
                                               const float* __restrict__ bias,
                                               const int* __restrict__ deg_out,
                                               __half* __restrict__ out16,
                                               float* __restrict__ out32, int n) {
  __shared__ _Float16 As[16 * 136];
  const int wave = threadIdx.x >> 6;
  const int lane = threadIdx.x & 63;
  const int sub  = lane & 15;
  const int grp  = lane >> 4;
  const int sh   = grp << 4;
  const u32 sub16 = (u32)sub * 16u;
  const int rowBase = blockIdx.x * 16;
  const char* __restrict__ xb = (const char*)xh;

  // ---- gather phase: 2 rows per wave
  {
    int r0 = rowBase + wave * 2, r1 = r0 + 1;
    int d0 = (r0 < n) ? deg_in[r0] : 0;
    int d1 = (r1 < n) ? deg_in[r1] : 0;
    int l0 = d0 > ELL_PAD ? ELL_PAD : d0;
    int l1 = d1 > ELL_PAD ? ELL_PAD : d1;
    int t0 = (l0 + 3) & ~3;
    int t1 = (l1 + 3) & ~3;
    const u16* ep0 = ell + (u32)(r0 < n ? r0 : 0) * ELL_PAD;
    const u16* ep1 = ell + (u32)(r1 < n ? r1 : 0) * ELL_PAD;

    float a0[8] = {0.f, 0.f, 0.f, 0.f, 0.f, 0.f, 0.f, 0.f};
    float a1[8] = {0.f, 0.f, 0.f, 0.f, 0.f, 0.f, 0.f, 0.f};

    int m = t0 < t1 ? t0 : t1;
    int e = 0;
    for (; e + 8 <= m; e += 8) {
      u64 wa0 = *(const u64*)&ep0[e];
      u64 wa1 = *(const u64*)&ep0[e + 4];
      u64 wb0 = *(const u64*)&ep1[e];
      u64 wb1 = *(const u64*)&ep1[e + 4];
      u32 ia0 = ((u32)(wa0 >> sh) & 0xFFFFu) * 256u + sub16;
      u32 ia1 = ((u32)(wa1 >> sh) & 0xFFFFu) * 256u + sub16;
      u32 ib0 = ((u32)(wb0 >> sh) & 0xFFFFu) * 256u + sub16;
      u32 ib1 = ((u32)(wb1 >> sh) & 0xFFFFu) * 256u + sub16;
      half8 va0 = *(const half8*)(xb + ia0);
      half8 va1 = *(const half8*)(xb + ia1);
      half8 vb0 = *(const half8*)(xb + ib0);
      half8 vb1 = *(const half8*)(xb + ib1);
#pragma unroll
      for (int j = 0; j < 8; j++) {
        a0[j] += (float)va0[j] + (float)va1[j];
        a1[j] += (float)vb0[j] + (float)vb1[j];
      }
    }
    for (; e < m; e += 4) {
      u64 wa = *(const u64*)&ep0[e];
      u64 wb = *(const u64*)&ep1[e];
      u32 ia = ((u32)(wa >> sh) & 0xFFFFu) * 256u + sub16;
      u32 ib = ((u32)(wb >> sh) & 0xFFFFu) * 256u + sub16;
      half8 va = *(const half8*)(xb + ia);
      half8 vb = *(const half8*)(xb + ib);
#pragma unroll
      for (int j = 0; j < 8; j++) { a0[j] += (float)va[j]; a1[j] += (float)vb[j]; }
    }
    for (int ea = m; ea < t0; ea += 4) {
      u64 wa = *(const u64*)&ep0[ea];
      u32 ia = ((u32)(wa >> sh) & 0xFFFFu) * 256u + sub16;
      half8 va = *(const half8*)(xb + ia);
#pragma unroll
      for (int j = 0; j < 8; j++) a0[j] += (float)va[j];
    }
    for (int eb = m; eb < t1; eb += 4) {
      u64 wb = *(const u64*)&ep1[eb];
      u32 ib = ((u32)(wb >> sh) & 0xFFFFu) * 256u + sub16;
      half8 vb = *(const half8*)(xb + ib);
#pragma unroll
      for (int j = 0; j < 8; j++) a1[j] += (float)vb[j];
    }

#pragma unroll
    for (int j = 0; j < 8; j++) {
      a0[j] += __shfl_xor(a0[j], 16, 64);
      a0[j] += __shfl_xor(a0[j], 32, 64);
      a1[j] += __shfl_xor(a1[j], 16, 64);
      a1[j] += __shfl_xor(a1[j], 32, 64);
    }

    float si0 = rsqrtf((float)(d0 < 1 ? 1 : d0));
    float si1 = rsqrtf((float)(d1 < 1 ? 1 : d1));
    if (grp == 0) {
      half8 h0, h1;
#pragma unroll
      for (int j = 0; j < 8; j++) {
        h0[j] = (_Float16)(a0[j] * si0);
        h1[j] = (_Float16)(a1[j] * si1);
      }
      *(half8*)&As[(wave * 2 + 0) * 136 + sub * 8] = h0;
      *(half8*)&As[(wave * 2 + 1) * 136 + sub * 8] = h1;
    }
  }
  __syncthreads();

  // ---- GEMM phase: wave w computes C[0:16, w*16:(w+1)*16]
  f32x4 acc = (f32x4){0.f, 0.f, 0.f, 0.f};
#pragma unroll
  for (int ks = 0; ks < 4; ks++) {
    half8 a  = *(const half8*)&As[(size_t)sub * 136 + ks * 32 + grp * 8];
    half8 bh = *(const half8*)&Whi[((wave * 4 + ks) * 64 + lane) * 8];
    half8 bl = *(const half8*)&Wlo[((wave * 4 + ks) * 64 + lane) * 8];
    acc = __builtin_amdgcn_mfma_f32_16x16x32_f16(a, bh, acc, 0, 0, 0);
    acc = __builtin_amdgcn_mfma_f32_16x16x32_f16(a, bl, acc, 0, 0, 0);
  }

  // C/D: col = lane&15 (+wave*16), row = grp*4 + reg  [m89-verified mapping]
  const int r0c = rowBase + grp * 4;
  const int col = wave * 16 + sub;
  const float bv = bias[col];
#pragma unroll
  for (int r = 0; r < 4; r++) {
    int row = r0c + r;
    if (row < n) {
      float v = fmaxf(acc[r] + bv, 0.f);
      if (out16) {
        int d = deg_out[row]; if (d < 1) d = 1;
        out16[(size_t)row * 128 + col] = __float2half(v * rsqrtf((float)d));
      } else {
        out32[(size_t)row * 128 + col] = v;
      }
    }
  }
}

// ---------- launch ----------

extern "C" void kernel_launch(void* const* d_in, const int* in_sizes, int n_in,
                              void* d_out, int out_size, void* d_ws, size_t ws_size,
                              hipStream_t stream) {
  const float* x   = (const float*)d_in[0];
  const float* Ws  = (const float*)d_in[1];
  const float* bs  = (const float*)d_in[2];
  const int* esrc  = (const int*)d_in[3];
  const int* edst  = (const int*)d_in[4];

  const int D = 128;
  const int N = in_sizes[0] / D;
  const int E = in_sizes[3];
  const int L = in_sizes[1] / (D * D);
  const int Npad = ((N + 15) / 16) * 16;
  const int NA = (E + EPB - 1) / EPB;        // 625 for E=640K
  const int NB = (N + BKT - 1) / BKT;        // 782 for N=50K

  char* base = (char*)d_ws;
  size_t off = 0;
  auto alloc = [&](size_t bytes) {
    char* p = base + off;
    off = (off + bytes + 255) & ~(size_t)255;
    return p;
  };
  int*      deg_out = (int*)alloc((size_t)N * 4);
  int*      deg_in  = (int*)alloc((size_t)N * 4);
  u16*      ell     = (u16*)alloc((size_t)N * ELL_PAD * 2);
  _Float16* Whi     = (_Float16*)alloc((size_t)L * 16384 * 2);
  _Float16* Wlo     = (_Float16*)alloc((size_t)L * 16384 * 2);
  _Float16* xh0     = (_Float16*)alloc((size_t)(Npad + 16) * 128 * 2);
  _Float16* xh1     = (_Float16*)alloc((size_t)(Npad + 16) * 128 * 2);
  u32*      part    = (u32*)alloc((size_t)NA * EPB * 4);
  u32*      runTab  = (u32*)alloc((size_t)NA * (NB + 1) * 4);
  u16*      partS   = (u16*)alloc((size_t)NA * EPB * 2);
  u32*      runTabS = (u32*)alloc((size_t)NA * (NB + 1) * 4);

  const int packTotal = L * 2048;
  const int packB = (packTotal + 255) / 256;
  const int padU32 = 16 * 64;

  initpack<<<dim3(1 + packB), dim3(256), 0, stream>>>(
      (u32*)(xh0 + (size_t)N * 128), (u32*)(xh1 + (size_t)N * 128),
      Ws, Whi, Wlo, padU32, packTotal);
  parta<<<dim3(NA), dim3(512), 0, stream>>>(
      esrc, edst, part, runTab, partS, runTabS, E, NB);
  partb<<<dim3(NB), dim3(512), 0, stream>>>(
      part, runTab, partS, runTabS, x, deg_out, deg_in, ell,
      (__half2*)xh0, N, NA, NB);

  float* outf = (float*)d_out;
  _Float16* ping[2] = {xh0, xh1};
  const dim3 lgrid(Npad / 16), lblk(512);

  for (int l = 0; l < L; l++) {
    bool last = (l == L - 1);
    layer16<<<lgrid, lblk, 0, stream>>>(
        (const _Float16*)ping[l & 1], deg_in, ell,
        Whi + (size_t)l * 16384, Wlo + (size_t)l * 16384,
        bs + (size_t)l * D, deg_out,
        last ? nullptr : (__half*)ping[(l + 1) & 1],
        last ? outf : nullptr, N);
  }
}

// Round 14
// 219.790 us; speedup vs baseline: 1.6609x; 1.0123x over previous
//
#include <hip/hip_runtime.h>
#include <hip/hip_fp16.h>

typedef __attribute__((ext_vector_type(8))) _Float16 half8;
typedef __attribute__((ext_vector_type(4))) float f32x4;
typedef unsigned int u32;
typedef unsigned short u16;
typedef unsigned long long u64;

#define ELL_PAD 64
#define BKT 64           // nodes per bucket (both src and dst sides)
#define BKT_SH 6
#define EPB 1024         // edges per parta block (625 blocks for E=640K)
#define NAMAX 640
#define RUNCAP 1536      // staged-pairs capacity (dst bucket load ~819 +- 29)

// wave-level inclusive scan (64 lanes, register-only, no barriers)
__device__ __forceinline__ u32 wscan(u32 v, int lane) {
#pragma unroll
  for (int off = 1; off < 64; off <<= 1) {
    u32 t = __shfl_up(v, off, 64);
    if (lane >= off) v += t;
  }
  return v;
}

// ---------- K1: DUAL counting sort + fused {phantom-zero, W-pack} ----------
// Blocks [0,NA): partition. Block NA: phantom xh pad rows. Blocks >NA: W pack.
// ZERO global atomics. Scans are wave-shfl based: 2 barriers total per block
// (vs 36 Hillis-Steele barrier-rounds) — the build was latency-exposed at
// ~2.4 blocks/CU where every barrier round's latency is serial.

__global__ __launch_bounds__(512) void parta(const int* __restrict__ esrc,
                                             const int* __restrict__ edst,
                                             u32* __restrict__ part,
                                             u32* __restrict__ runTab,
                                             u16* __restrict__ partS,
                                             u32* __restrict__ runTabS,
                                             u32* __restrict__ xz0,
                                             u32* __restrict__ xz1,
                                             const float* __restrict__ Ws,
                                             _Float16* __restrict__ Whi,
                                             _Float16* __restrict__ Wlo,
                                             int E, int NB, int NA,
                                             int padU32, int packTotal) {
  int a = blockIdx.x;
  int tid = threadIdx.x;
  if (a >= NA) {
    if (a == NA) {            // phantom pad rows of both ping buffers
      for (int j = tid; j < padU32; j += 512) { xz0[j] = 0; xz1[j] = 0; }
      return;
    }
    // W pack: elem j of (layer,ntile,kstep,lane) =
    // W[k=kstep*32+(lane>>4)*8+j][n=ntile*16+(lane&15)]
    int i = (a - NA - 1) * 512 + tid;
    if (i < packTotal) {
      int lane  = i & 63;
      int kstep = (i >> 6) & 3;
      int ntile = (i >> 8) & 7;
      int layer = i >> 11;
      int nn = ntile * 16 + (lane & 15);
      int k0 = kstep * 32 + (lane >> 4) * 8;
      const float* W = Ws + (size_t)layer * 128 * 128;
      size_t base = (size_t)i * 8;
      for (int j = 0; j < 8; j++) {
        float v = W[(k0 + j) * 128 + nn];
        _Float16 hi = (_Float16)v;
        Whi[base + j] = hi;
        Wlo[base + j] = (_Float16)(v - (float)hi);   // exact residual
      }
    }
    return;
  }

  __shared__ u32 histD[1024];     // NB+1 <= 1024
  __shared__ u32 histS[1024];
  __shared__ u32 stageD[EPB];     // 4 KB
  __shared__ u16 stageS[EPB];     // 2 KB
  __shared__ u32 wsum[8];
  const int lane = tid & 63, wid = tid >> 6;
  int e0 = a * EPB;
  int e1 = min(E, e0 + EPB);
  int len = e1 - e0;
  for (int j = tid; j <= NB; j += 512) { histD[j] = 0; histS[j] = 0; }
  __syncthreads();
  // pass 1: dual histogram (LDS only)
  for (int i = e0 + tid; i < e1; i += 512) {
    int s = esrc[i];
    int d = edst[i];
    atomicAdd(&histD[d >> BKT_SH], 1u);
    atomicAdd(&histS[s >> BKT_SH], 1u);
  }
  __syncthreads();
  // scan D: wave-shfl, ONE barrier
  {
    int i0 = 2 * tid, i1 = i0 + 1;
    u32 c0 = (i0 < NB) ? histD[i0] : 0;
    u32 c1 = (i1 < NB) ? histD[i1] : 0;
    u32 s2 = c0 + c1;
    u32 incl = wscan(s2, lane);
    if (lane == 63) wsum[wid] = incl;
    __syncthreads();
    u32 wpre = 0;
#pragma unroll
    for (int w = 0; w < 8; w++) { u32 t = wsum[w]; wpre += (w < wid) ? t : 0; }
    u32 excl = wpre + incl - s2;
    u32* rt = runTab + (size_t)a * (NB + 1);
    if (i0 < NB) { rt[i0] = excl;      histD[i0] = excl; }
    if (i1 < NB) { rt[i1] = excl + c0; histD[i1] = excl + c0; }
    if (tid == 0) rt[NB] = (u32)len;
  }
  __syncthreads();   // wsum reuse + histD cursors visible
  // scan S: wave-shfl, ONE barrier
  {
    int i0 = 2 * tid, i1 = i0 + 1;
    u32 c0 = (i0 < NB) ? histS[i0] : 0;
    u32 c1 = (i1 < NB) ? histS[i1] : 0;
    u32 s2 = c0 + c1;
    u32 incl = wscan(s2, lane);
    if (lane == 63) wsum[wid] = incl;
    __syncthreads();
    u32 wpre = 0;
#pragma unroll
    for (int w = 0; w < 8; w++) { u32 t = wsum[w]; wpre += (w < wid) ? t : 0; }
    u32 excl = wpre + incl - s2;
    u32* rt = runTabS + (size_t)a * (NB + 1);
    if (i0 < NB) { rt[i0] = excl;      histS[i0] = excl; }
    if (i1 < NB) { rt[i1] = excl + c0; histS[i1] = excl + c0; }
    if (tid == 0) rt[NB] = (u32)len;
  }
  __syncthreads();
  // pass 2: place into both stagings (edges L2-hot re-read)
  for (int i = e0 + tid; i < e1; i += 512) {
    int s = esrc[i];
    int d = edst[i];
    u32 pD = atomicAdd(&histD[d >> BKT_SH], 1u);
    stageD[pD] = (u32)s | ((u32)(d & (BKT - 1)) << 16);
    u32 pS = atomicAdd(&histS[s >> BKT_SH], 1u);
    stageS[pS] = (u16)(s & (BKT - 1));
  }
  __syncthreads();
  // pass 3: dense coalesced writes
  u32* opD = part + (size_t)a * EPB;
  for (int j = tid; j < len; j += 512) opD[j] = stageD[j];
  u16* opS = partS + (size_t)a * EPB;
  for (int j = tid; j < len; j += 512) opS[j] = stageS[j];
}

// ---------- K2: per-bucket ELL build + src-count deg_out + fused xscale ----------
// Wave-shfl run scan (1 barrier vs 18 rounds). Zero global atomics.

__global__ __launch_bounds__(512) void partb(const u32* __restrict__ part,
                                             const u32* __restrict__ runTab,
                                             const u16* __restrict__ partS,
                                             const u32* __restrict__ runTabS,
                                             const float* __restrict__ x,
                                             int* __restrict__ deg_out,
                                             int* __restrict__ deg_in,
                                             u16* __restrict__ ell,
                                             __half2* __restrict__ xh,
                                             int N, int NA, int NB) {
  __shared__ u16 slice[BKT * ELL_PAD];   // 8 KB
  __shared__ u32 cnt2[BKT * 17];         // 4.3 KB
  __shared__ u32 roff[NAMAX + 1];
  __shared__ u32 rbase[NAMAX];
  __shared__ u16 runid[RUNCAP];          // 3 KB
  __shared__ u32 pstage[RUNCAP];         // 6 KB
  __shared__ u32 wsum[8];
  __shared__ u32 cntS[BKT];
  __shared__ float sc[BKT];
  int b = blockIdx.x;
  int base = b * BKT;
  int hi = min(BKT, N - base);
  if (hi <= 0) return;
  int tid = threadIdx.x;
  const int lane = tid & 63, wid = tid >> 6;

  u32 nv = ((u32)N << 16) | (u32)N;      // two phantom entries
  u32* s32 = (u32*)slice;
  for (int j = tid; j < BKT * (ELL_PAD / 2); j += 512) s32[j] = nv;
  for (int j = tid; j < BKT * 17; j += 512) cnt2[j] = 0;
  if (tid < BKT) cntS[tid] = 0;
  // dst-side run lengths (2/thread) + wave-shfl scan
  int a0 = 2 * tid, a1 = a0 + 1;
  u32 l0 = 0, l1 = 0;
  if (a0 < NA) {
    u32 s = runTab[(size_t)a0 * (NB + 1) + b];
    u32 e = runTab[(size_t)a0 * (NB + 1) + b + 1];
    l0 = e - s;
    rbase[a0] = (u32)a0 * EPB + s;
  }
  if (a1 < NA) {
    u32 s = runTab[(size_t)a1 * (NB + 1) + b];
    u32 e = runTab[(size_t)a1 * (NB + 1) + b + 1];
    l1 = e - s;
    rbase[a1] = (u32)a1 * EPB + s;
  }
  u32 s2 = l0 + l1;
  u32 incl = wscan(s2, lane);
  if (lane == 63) wsum[wid] = incl;
  __syncthreads();
  u32 wpre = 0;
#pragma unroll
  for (int w = 0; w < 8; w++) { u32 t = wsum[w]; wpre += (w < wid) ? t : 0; }
  u32 pbase = wpre + incl - s2;
  if (a0 < NA) roff[a0] = pbase;
  if (a1 < NA) roff[a1] = pbase + l0;
  if (tid == 511) roff[NA] = wpre + incl;   // grand total
  __syncthreads();
  int T = (int)roff[NA];
  // inverse map: runid[i] = run containing flattened item i
  for (int a = tid; a < NA; a += 512) {
    u32 s0 = roff[a];
    u32 l = roff[a + 1] - s0;
    for (u32 k = 0; k < l; k++)
      if (s0 + k < RUNCAP) runid[s0 + k] = (u16)a;
  }
  __syncthreads();
  // src-side count (LDS atomics) — overlaps dst-side latency
  for (int a = tid; a < NA; a += 512) {
    u32 s = runTabS[(size_t)a * (NB + 1) + b];
    u32 e = runTabS[(size_t)a * (NB + 1) + b + 1];
    const u16* ps = partS + (size_t)a * EPB;
    for (u32 k = s; k < e; k++) atomicAdd(&cntS[ps[k]], 1u);
  }
  // dst pass A: read part once, stage pair, count (row, srcbucket)
  for (int i = tid; i < T; i += 512) {
    int a;
    if (i < RUNCAP) a = runid[i];
    else {
      int lo = 0, hh = NA;
      while (hh - lo > 1) { int mid = (lo + hh) >> 1; if (roff[mid] <= (u32)i) lo = mid; else hh = mid; }
      a = lo;
    }
    u32 pair = part[(size_t)rbase[a] + ((u32)i - roff[a])];
    if (i < RUNCAP) pstage[i] = pair;
    u32 dl = pair >> 16;
    u32 src = pair & 0xFFFFu;
    atomicAdd(&cnt2[dl * 17 + (src >> 12)], 1u);
  }
  __syncthreads();
  // per-row exclusive prefix over 16 src-buckets; emit deg_in + deg_out
  if (tid < BKT) {
    u32 run = 0;
    for (int bk = 0; bk < 16; bk++) {
      u32 t2 = cnt2[tid * 17 + bk];
      cnt2[tid * 17 + bk] = run;
      run += t2;
    }
    if (tid < hi) {
      deg_in[base + tid] = (int)run;
      deg_out[base + tid] = (int)cntS[tid];
    }
  }
  __syncthreads();
  // dst pass B: place at bucket cursors -> row sorted by src bucket
  for (int i = tid; i < T; i += 512) {
    u32 pair;
    if (i < RUNCAP) pair = pstage[i];
    else {
      int lo = 0, hh = NA;
      while (hh - lo > 1) { int mid = (lo + hh) >> 1; if (roff[mid] <= (u32)i) lo = mid; else hh = mid; }
      pair = part[(size_t)rbase[lo] + ((u32)i - roff[lo])];
    }
    u32 dl = pair >> 16;
    u32 src = pair & 0xFFFFu;
    u32 p = atomicAdd(&cnt2[dl * 17 + (src >> 12)], 1u);
    if (p < ELL_PAD) slice[dl * ELL_PAD + p] = (u16)src;
  }
  __syncthreads();
  u32* eg = (u32*)(ell + (size_t)base * ELL_PAD);
  for (int j = tid; j < hi * (ELL_PAD / 2); j += 512) eg[j] = s32[j];
  // ---- fused xscale for rows [base, base+hi) using this bucket's cntS
  if (tid < hi) {
    u32 d = cntS[tid]; if (d < 1) d = 1;
    sc[tid] = rsqrtf((float)d);
  }
  __syncthreads();
  for (int j = tid; j < hi * 64; j += 512) {
    int r = j >> 6, c = j & 63;
    float s = sc[r];
    float2 v = ((const float2*)x)[(size_t)(base + r) * 64 + c];
    xh[(size_t)(base + r) * 64 + c] = __floats2half2_rn(v.x * s, v.y * s);
  }
}

// ---------- K3: fused layer — 16-row tile, 8 waves (measured at its
// random-gather roofline ~4.5 TB/s — unchanged) ----------

__global__ __launch_bounds__(512) void layer16(const _Float16* __restrict__ xh,
                                               const int* __restrict__ deg_in,
                                               const u16* __restrict__ ell,
                                               const _Float16* __restrict__ Whi,
                                               const _Float16* __restrict__ Wlo,
                                               const float* __restrict__ bias,
                                               const int* __restrict__ deg_out,
                                               __half* __restrict__ out16,
                                               float* __restrict__ out32, int n) {
  __shared__ _Float16 As[16 * 136];
  const int wave = threadIdx.x >> 6;
  const int lane = threadIdx.x & 63;
  const int sub  = lane & 15;
  const int grp  = lane >> 4;
  const int sh   = grp << 4;
  const u32 sub16 = (u32)sub * 16u;
  const int rowBase = blockIdx.x * 16;
  const char* __restrict__ xb = (const char*)xh;

  // ---- gather phase: 2 rows per wave
  {
    int r0 = rowBase + wave * 2, r1 = r0 + 1;
    int d0 = (r0 < n) ? deg_in[r0] : 0;
    int d1 = (r1 < n) ? deg_in[r1] : 0;
    int l0 = d0 > ELL_PAD ? ELL_PAD : d0;
    int l1 = d1 > ELL_PAD ? ELL_PAD : d1;
    int t0 = (l0 + 3) & ~3;
    int t1 = (l1 + 3) & ~3;
    const u16* ep0 = ell + (u32)(r0 < n ? r0 : 0) * ELL_PAD;
    const u16* ep1 = ell + (u32)(r1 < n ? r1 : 0) * ELL_PAD;

    float a0[8] = {0.f, 0.f, 0.f, 0.f, 0.f, 0.f, 0.f, 0.f};
    float a1[8] = {0.f, 0.f, 0.f, 0.f, 0.f, 0.f, 0.f, 0.f};

    int m = t0 < t1 ? t0 : t1;
    int e = 0;
    for (; e + 8 <= m; e += 8) {
      u64 wa0 = *(const u64*)&ep0[e];
      u64 wa1 = *(const u64*)&ep0[e + 4];
      u64 wb0 = *(const u64*)&ep1[e];
      u64 wb1 = *(const u64*)&ep1[e + 4];
      u32 ia0 = ((u32)(wa0 >> sh) & 0xFFFFu) * 256u + sub16;
      u32 ia1 = ((u32)(wa1 >> sh) & 0xFFFFu) * 256u + sub16;
      u32 ib0 = ((u32)(wb0 >> sh) & 0xFFFFu) * 256u + sub16;
      u32 ib1 = ((u32)(wb1 >> sh) & 0xFFFFu) * 256u + sub16;
      half8 va0 = *(const half8*)(xb + ia0);
      half8 va1 = *(const half8*)(xb + ia1);
      half8 vb0 = *(const half8*)(xb + ib0);
      half8 vb1 = *(const half8*)(xb + ib1);
#pragma unroll
      for (int j = 0; j < 8; j++) {
        a0[j] += (float)va0[j] + (float)va1[j];
        a1[j] += (float)vb0[j] + (float)vb1[j];
      }
    }
    for (; e < m; e += 4) {
      u64 wa = *(const u64*)&ep0[e];
      u64 wb = *(const u64*)&ep1[e];
      u32 ia = ((u32)(wa >> sh) & 0xFFFFu) * 256u + sub16;
      u32 ib = ((u32)(wb >> sh) & 0xFFFFu) * 256u + sub16;
      half8 va = *(const half8*)(xb + ia);
      half8 vb = *(const half8*)(xb + ib);
#pragma unroll
      for (int j = 0; j < 8; j++) { a0[j] += (float)va[j]; a1[j] += (float)vb[j]; }
    }
    for (int ea = m; ea < t0; ea += 4) {
      u64 wa = *(const u64*)&ep0[ea];
      u32 ia = ((u32)(wa >> sh) & 0xFFFFu) * 256u + sub16;
      half8 va = *(const half8*)(xb + ia);
#pragma unroll
      for (int j = 0; j < 8; j++) a0[j] += (float)va[j];
    }
    for (int eb = m; eb < t1; eb += 4) {
      u64 wb = *(const u64*)&ep1[eb];
      u32 ib = ((u32)(wb >> sh) & 0xFFFFu) * 256u + sub16;
      half8 vb = *(const half8*)(xb + ib);
#pragma unroll
      for (int j = 0; j < 8; j++) a1[j] += (float)vb[j];
    }

#pragma unroll
    for (int j = 0; j < 8; j++) {
      a0[j] += __shfl_xor(a0[j], 16, 64);
      a0[j] += __shfl_xor(a0[j], 32, 64);
      a1[j] += __shfl_xor(a1[j], 16, 64);
      a1[j] += __shfl_xor(a1[j], 32, 64);
    }

    float si0 = rsqrtf((float)(d0 < 1 ? 1 : d0));
    float si1 = rsqrtf((float)(d1 < 1 ? 1 : d1));
    if (grp == 0) {
      half8 h0, h1;
#pragma unroll
      for (int j = 0; j < 8; j++) {
        h0[j] = (_Float16)(a0[j] * si0);
        h1[j] = (_Float16)(a1[j] * si1);
      }
      *(half8*)&As[(wave * 2 + 0) * 136 + sub * 8] = h0;
      *(half8*)&As[(wave * 2 + 1) * 136 + sub * 8] = h1;
    }
  }
  __syncthreads();

  // ---- GEMM phase: wave w computes C[0:16, w*16:(w+1)*16]
  f32x4 acc = (f32x4){0.f, 0.f, 0.f, 0.f};
#pragma unroll
  for (int ks = 0; ks < 4; ks++) {
    half8 a  = *(const half8*)&As[(size_t)sub * 136 + ks * 32 + grp * 8];
    half8 bh = *(const half8*)&Whi[((wave * 4 + ks) * 64 + lane) * 8];
    half8 bl = *(const half8*)&Wlo[((wave * 4 + ks) * 64 + lane) * 8];
    acc = __builtin_amdgcn_mfma_f32_16x16x32_f16(a, bh, acc, 0, 0, 0);
    acc = __builtin_amdgcn_mfma_f32_16x16x32_f16(a, bl, acc, 0, 0, 0);
  }

  // C/D: col = lane&15 (+wave*16), row = grp*4 + reg  [m89-verified mapping]
  const int r0c = rowBase + grp * 4;
  const int col = wave * 16 + sub;
  const float bv = bias[col];
#pragma unroll
  for (int r = 0; r < 4; r++) {
    int row = r0c + r;
    if (row < n) {
      float v = fmaxf(acc[r] + bv, 0.f);
      if (out16) {
        int d = deg_out[row]; if (d < 1) d = 1;
        out16[(size_t)row * 128 + col] = __float2half(v * rsqrtf((float)d));
      } else {
        out32[(size_t)row * 128 + col] = v;
      }
    }
  }
}

// ---------- launch ----------

extern "C" void kernel_launch(void* const* d_in, const int* in_sizes, int n_in,
                              void* d_out, int out_size, void* d_ws, size_t ws_size,
                              hipStream_t stream) {
  const float* x   = (const float*)d_in[0];
  const float* Ws  = (const float*)d_in[1];
  const float* bs  = (const float*)d_in[2];
  const int* esrc  = (const int*)d_in[3];
  const int* edst  = (const int*)d_in[4];

  const int D = 128;
  const int N = in_sizes[0] / D;
  const int E = in_sizes[3];
  const int L = in_sizes[1] / (D * D);
  const int Npad = ((N + 15) / 16) * 16;
  const int NA = (E + EPB - 1) / EPB;        // 625 for E=640K
  const int NB = (N + BKT - 1) / BKT;        // 782 for N=50K

  char* base = (char*)d_ws;
  size_t off = 0;
  auto alloc = [&](size_t bytes) {
    char* p = base + off;
    off = (off + bytes + 255) & ~(size_t)255;
    return p;
  };
  int*      deg_out = (int*)alloc((size_t)N * 4);
  int*      deg_in  = (int*)alloc((size_t)N * 4);
  u16*      ell     = (u16*)alloc((size_t)N * ELL_PAD * 2);
  _Float16* Whi     = (_Float16*)alloc((size_t)L * 16384 * 2);
  _Float16* Wlo     = (_Float16*)alloc((size_t)L * 16384 * 2);
  _Float16* xh0     = (_Float16*)alloc((size_t)(Npad + 16) * 128 * 2);
  _Float16* xh1     = (_Float16*)alloc((size_t)(Npad + 16) * 128 * 2);
  u32*      part    = (u32*)alloc((size_t)NA * EPB * 4);
  u32*      runTab  = (u32*)alloc((size_t)NA * (NB + 1) * 4);
  u16*      partS   = (u16*)alloc((size_t)NA * EPB * 2);
  u32*      runTabS = (u32*)alloc((size_t)NA * (NB + 1) * 4);

  const int packTotal = L * 2048;
  const int packB = (packTotal + 511) / 512;
  const int padU32 = 16 * 64;

  parta<<<dim3(NA + 1 + packB), dim3(512), 0, stream>>>(
      esrc, edst, part, runTab, partS, runTabS,
      (u32*)(xh0 + (size_t)N * 128), (u32*)(xh1 + (size_t)N * 128),
      Ws, Whi, Wlo, E, NB, NA, padU32, packTotal);
  partb<<<dim3(NB), dim3(512), 0, stream>>>(
      part, runTab, partS, runTabS, x, deg_out, deg_in, ell,
      (__half2*)xh0, N, NA, NB);

  float* outf = (float*)d_out;
  _Float16* ping[2] = {xh0, xh1};
  const dim3 lgrid(Npad / 16), lblk(512);

  for (int l = 0; l < L; l++) {
    bool last = (l == L - 1);
    layer16<<<lgrid, lblk, 0, stream>>>(
        (const _Float16*)ping[l & 1], deg_in, ell,
        Whi + (size_t)l * 16384, Wlo + (size_t)l * 16384,
        bs + (size_t)l * D, deg_out,
        last ? nullptr : (__half*)ping[(l + 1) & 1],
        last ? outf : nullptr, N);
  }
}